// Round 2
// baseline (231.725 us; speedup 1.0000x reference)
//
#include <hip/hip_runtime.h>

#define M_DIM   96
#define IN_DIM  16
#define OUT_DIM 16
#define N_BATCH 4
#define CHUNK   4                      // i-planes written per block
#define PLANE4  (M_DIM * M_DIM / 4)    // 2304 float4 per plane

typedef float f4 __attribute__((ext_vector_type(4)));

// out[n,s,i,j,k] = Y0[n,s,i] + Y1[n,s,j] + Y2[n,s,k] + S[n,s] + bias[s]
// Write-BW bound: 226.5 MB out. One block per (n,s, 4-plane chunk); grid 1536.
// Preamble (tiny dots + wave-shuffle reduce) amortized over 4 planes; store
// loop reuses each LDS row read across the 4 planes (loop interchange).
__global__ __launch_bounds__(256) void eq13_kernel(
    const float* __restrict__ x,      // (N, IN_DIM, M)
    const float* __restrict__ coefs,  // (IN_DIM, OUT_DIM, 4)
    const float* __restrict__ bias,   // (OUT_DIM)
    f4* __restrict__ out4)            // (N, OUT_DIM, M, M, M) as float4
{
    __shared__ float s_y0[M_DIM];
    __shared__ float s_y1[M_DIM];
    __shared__ __align__(16) float s_y2[M_DIM];
    __shared__ float s_red[M_DIM];
    __shared__ float s_S;

    const int bid     = blockIdx.x;            // 0 .. 64*24-1
    const int nchunks = M_DIM / CHUNK;         // 24
    const int ns      = bid / nchunks;         // n*16 + s
    const int i0      = (bid - ns * nchunks) * CHUNK;
    const int n       = ns >> 4;
    const int s       = ns & 15;
    const int t       = threadIdx.x;

    if (t < M_DIM) {
        float y0 = 0.f, y1 = 0.f, y2 = 0.f, y3 = 0.f;
        const float* xb = x + (size_t)n * IN_DIM * M_DIM + t;   // coalesced over t
        const float* cb = coefs + s * 4;
        #pragma unroll
        for (int d = 0; d < IN_DIM; ++d) {
            float xv = xb[d * M_DIM];
            f4 c4 = *(const f4*)(cb + d * OUT_DIM * 4);  // c[d][s][0..3]
            y0 = fmaf(xv, c4.x, y0);
            y1 = fmaf(xv, c4.y, y1);
            y2 = fmaf(xv, c4.z, y2);
            y3 = fmaf(xv, c4.w, y3);
        }
        s_y0[t]  = y0;
        s_y1[t]  = y1;
        s_y2[t]  = y2;
        s_red[t] = y3;
    }
    __syncthreads();

    // Parallel reduction of s_red[0..95] on wave 0 (all 64 lanes active).
    if (t < 64) {
        float v = s_red[t] + ((t < 32) ? s_red[t + 64] : 0.f);
        #pragma unroll
        for (int off = 32; off; off >>= 1) v += __shfl_down(v, off);
        if (t == 0) s_S = v + bias[s];
    }
    __syncthreads();

    const float S  = s_S;
    const float b0 = s_y0[i0 + 0] + S;
    const float b1 = s_y0[i0 + 1] + S;
    const float b2 = s_y0[i0 + 2] + S;
    const float b3 = s_y0[i0 + 3] + S;

    const f4* y2v = (const f4*)s_y2;                       // 24 x float4
    f4* dst = out4 + (size_t)(ns * M_DIM + i0) * PLANE4;   // 4 contiguous planes

    // 2304 float4 per plane = 9 iters x 256 threads; consecutive lanes ->
    // consecutive 16B stores. Each LDS row read feeds 4 plane stores.
    #pragma unroll
    for (int it = 0; it < 9; ++it) {
        int   c  = t + it * 256;          // 0 .. 2303
        int   j  = c / 24;                // row (0..95)
        int   kq = c - j * 24;            // float4 idx along k
        float w  = s_y1[j];
        f4    f  = y2v[kq];
        __builtin_nontemporal_store(f + (w + b0), dst + c);
        __builtin_nontemporal_store(f + (w + b1), dst + c + PLANE4);
        __builtin_nontemporal_store(f + (w + b2), dst + c + 2 * PLANE4);
        __builtin_nontemporal_store(f + (w + b3), dst + c + 3 * PLANE4);
    }
}

extern "C" void kernel_launch(void* const* d_in, const int* in_sizes, int n_in,
                              void* d_out, int out_size, void* d_ws, size_t ws_size,
                              hipStream_t stream) {
    const float* x     = (const float*)d_in[0];
    const float* coefs = (const float*)d_in[1];
    const float* bias  = (const float*)d_in[2];
    f4* out4 = (f4*)d_out;

    const int grid = N_BATCH * OUT_DIM * (M_DIM / CHUNK);   // 1536 blocks
    eq13_kernel<<<grid, 256, 0, stream>>>(x, coefs, bias, out4);
}

// Round 3
// 218.696 us; speedup vs baseline: 1.0596x; 1.0596x over previous
//
#include <hip/hip_runtime.h>

#define M_DIM   96
#define IN_DIM  16
#define OUT_DIM 16
#define N_BATCH 4
#define PLANE4  (M_DIM * M_DIM / 4)    // 2304 float4 per plane

typedef float f4 __attribute__((ext_vector_type(4)));

// out[n,s,i,j,k] = Y0[n,s,i] + Y1[n,s,j] + Y2[n,s,k] + S[n,s] + bias[s]
// Pure write-BW bound: 226.5 MB output, ~24 KB input. One block per (n,s,i)
// plane (grid 6144), 256 threads; plane streamed as 9x256 coalesced float4
// stores. R1 post-mortem: nontemporal stores + 4-plane chunking regressed
// (~+12 us) -- regular stores, one plane/block is the fastest structure.
__global__ __launch_bounds__(256) void eq13_kernel(
    const float* __restrict__ x,      // (N, IN_DIM, M)
    const float* __restrict__ coefs,  // (IN_DIM, OUT_DIM, 4)
    const float* __restrict__ bias,   // (OUT_DIM)
    f4* __restrict__ out4)            // (N, OUT_DIM, M, M, M) as float4
{
    __shared__ float s_y0[M_DIM];
    __shared__ float s_y1[M_DIM];
    __shared__ __align__(16) float s_y2[M_DIM];
    __shared__ float s_red[M_DIM];
    __shared__ float s_S;

    const int bid = blockIdx.x;          // 0 .. 6143
    const int ns  = bid / M_DIM;         // n*16 + s
    const int i   = bid - ns * M_DIM;
    const int n   = ns >> 4;
    const int s   = ns & 15;
    const int t   = threadIdx.x;

    if (t < M_DIM) {
        float y0 = 0.f, y1 = 0.f, y2 = 0.f, y3 = 0.f;
        const float* xb = x + (size_t)n * IN_DIM * M_DIM + t;   // coalesced over t
        const float* cb = coefs + s * 4;
        #pragma unroll
        for (int d = 0; d < IN_DIM; ++d) {
            float xv = xb[d * M_DIM];
            f4 c4 = *(const f4*)(cb + d * OUT_DIM * 4);  // c[d][s][0..3]
            y0 = fmaf(xv, c4.x, y0);
            y1 = fmaf(xv, c4.y, y1);
            y2 = fmaf(xv, c4.z, y2);
            y3 = fmaf(xv, c4.w, y3);
        }
        s_y0[t]  = y0;
        s_y1[t]  = y1;
        s_y2[t]  = y2;
        s_red[t] = y3;
    }
    __syncthreads();

    // Parallel reduction of s_red[0..95] on wave 0 (shuffle, no serial loop).
    if (t < 64) {
        float v = s_red[t] + ((t < 32) ? s_red[t + 64] : 0.f);
        #pragma unroll
        for (int off = 32; off; off >>= 1) v += __shfl_down(v, off);
        if (t == 0) s_S = v + bias[s];
    }
    __syncthreads();

    const float  base = s_y0[i] + s_S;
    const f4*    y2v  = (const f4*)s_y2;                 // 24 x float4
    f4* dst = out4 + (size_t)bid * PLANE4;               // this block's plane

    // 2304 float4 = 9 iters x 256 threads; consecutive lanes -> consecutive
    // 16B stores (perfectly coalesced). Plain stores (NT regressed in R1).
    #pragma unroll
    for (int it = 0; it < 9; ++it) {
        int   c  = t + it * 256;          // 0 .. 2303
        int   j  = c / 24;                // row (0..95)
        int   kq = c - j * 24;            // float4 idx along k
        float v  = base + s_y1[j];
        f4    f  = y2v[kq];
        f.x += v; f.y += v; f.z += v; f.w += v;
        dst[c] = f;
    }
}

extern "C" void kernel_launch(void* const* d_in, const int* in_sizes, int n_in,
                              void* d_out, int out_size, void* d_ws, size_t ws_size,
                              hipStream_t stream) {
    const float* x     = (const float*)d_in[0];
    const float* coefs = (const float*)d_in[1];
    const float* bias  = (const float*)d_in[2];
    f4* out4 = (f4*)d_out;

    const int grid = N_BATCH * OUT_DIM * M_DIM;   // 6144 blocks
    eq13_kernel<<<grid, 256, 0, stream>>>(x, coefs, bias, out4);
}